// Round 1
// 201.761 us; speedup vs baseline: 1.0111x; 1.0111x over previous
//
#include <hip/hip_runtime.h>

// CausalSelfAttention: B=2, S=2048, D=1024, H=16, Hd=64
// qkv = x@w_qkv+b ; per-head causal softmax(QK^T/8)V ; out = ao@w_proj+b
//
// Fragment layouts (gfx950, HW-verified per guide):
//   16x16x32: A[m=lane&15][k=(lane>>4)*8+j]; B[k][n=lane&15]; C/D col=lane&15,
//             row=(lane>>4)*4+reg
//   32x32x16: A[m=lane&31][k=(lane>>5)*8+j]; B[k=(lane>>5)*8+j][n=lane&31];
//             C/D col=lane&31, row=(reg&3)+8*(reg>>2)+4*(lane>>5)  [m74/m101]
//
// GEMMs: m97 structure. Attention (R10): swapped 32x32 QK^T so each lane owns
// one query's score row; P stays in registers via v_cvt_pk_bf16_f32 +
// v_permlane32_swap_b32 (T12) -> no P LDS round-trip, no lgkmcnt(0) drain.
// Row-sums via ones-column MFMA (lands in O's row layout -> no end shuffles).
// Triple-buffered K/V staging with prefetch distance 2 and a RAW barrier
// (s_waitcnt vmcnt(4); s_barrier) so the next tile's DMA stays in flight
// across the barrier (AITER-style, never vmcnt(0)). qg complement-paired
// across blockIdx.z for CU balance. p = exp2(score); log2e folded into Q
// pre-scale. s_setprio(1) around MFMA clusters (T5).

typedef float f32x4 __attribute__((ext_vector_type(4)));
typedef float f32x16 __attribute__((ext_vector_type(16)));
typedef short bf16x8 __attribute__((ext_vector_type(8)));

#if __has_builtin(__builtin_amdgcn_exp2f)
#define EXP2(x) __builtin_amdgcn_exp2f(x)
#else
#define EXP2(x) exp2f(x)
#endif

__device__ __forceinline__ unsigned short f2bf(float f) {
  union { float f; unsigned u; } v; v.f = f;
  unsigned u = v.u + 0x7fffu + ((v.u >> 16) & 1u);   // RNE
  return (unsigned short)(u >> 16);
}

// async global->LDS, 16 bytes per lane; lds base must be wave-uniform,
// lane l's data lands at lds_base + l*16 bytes (m104/m108 semantics).
__device__ __forceinline__ void async_load16(const void* g, void* lds) {
  __builtin_amdgcn_global_load_lds(
      (const __attribute__((address_space(1))) void*)g,
      (__attribute__((address_space(3))) void*)lds, 16, 0, 0);
}

// ---------------- prep: fp32 -> bf16 elementwise ----------------
__global__ void f32_to_bf16_kernel(const float* __restrict__ in,
                                   unsigned short* __restrict__ out, int n) {
  int i = (blockIdx.x * 256 + threadIdx.x) * 4;
  if (i < n) {
    float4 f = *(const float4*)(in + i);
    ushort4 o;
    o.x = f2bf(f.x); o.y = f2bf(f.y); o.z = f2bf(f.z); o.w = f2bf(f.w);
    *(ushort4*)(out + i) = o;
  }
}

// ---------------- prep: fp32 [K][N] -> bf16 [N][K] ----------------
__global__ void transpose_f32_bf16_kernel(const float* __restrict__ in,
                                          unsigned short* __restrict__ out,
                                          int K, int N) {
  __shared__ float tile[32][33];
  int n0 = blockIdx.x * 32, k0 = blockIdx.y * 32;
  int tx = threadIdx.x, ty = threadIdx.y;  // block (32,8)
#pragma unroll
  for (int i = ty; i < 32; i += 8)
    tile[i][tx] = in[(size_t)(k0 + i) * N + (n0 + tx)];
  __syncthreads();
#pragma unroll
  for (int i = ty; i < 32; i += 8)
    out[(size_t)(n0 + i) * K + (k0 + tx)] = f2bf(tile[tx][i]);
}

// ---------------- shared GEMM mainloop (m97 structure) ----------------
template <int MI, int NI>
__device__ __forceinline__ void gemm_mainloop(
    const unsigned short* __restrict__ A,   // [M][K] row-major bf16
    const unsigned short* __restrict__ BT,  // [N][K] row-major bf16
    int K, int mBlk, int nBlk,
    unsigned short* As, unsigned short* Bs,
    f32x4 (&acc)[MI][NI], int lane, int wave)
{
  const int l16 = lane & 15, quad = lane >> 4;
  const int mW = (wave >> 1) * MI * 16;
  const int nW = (wave & 1) * NI * 16;
  constexpr int AROWS = 2 * MI * 16;
  constexpr int BROWS = 2 * NI * 16;
  constexpr int AINST = AROWS / 64;
  constexpr int BINST = BROWS / 64;
  const int rl = lane >> 2;           // 16 rows per instruction
  const int cl = (lane & 3) * 8;      // 4 lanes cover one 32-elem row

  for (int k0 = 0; k0 < K; k0 += 32) {
    __syncthreads();
#pragma unroll
    for (int t = 0; t < AINST; ++t) {
      const int rbase = wave * (AROWS / 4) + t * 16;
      async_load16(A + (size_t)(mBlk + rbase + rl) * K + k0 + cl, &As[rbase * 32]);
    }
#pragma unroll
    for (int t = 0; t < BINST; ++t) {
      const int rbase = wave * (BROWS / 4) + t * 16;
      async_load16(BT + (size_t)(nBlk + rbase + rl) * K + k0 + cl, &Bs[rbase * 32]);
    }
    __syncthreads();

    bf16x8 af[MI], bf[NI];
#pragma unroll
    for (int i = 0; i < MI; ++i)
      af[i] = *(const bf16x8*)&As[(mW + i * 16 + l16) * 32 + quad * 8];
#pragma unroll
    for (int j = 0; j < NI; ++j)
      bf[j] = *(const bf16x8*)&Bs[(nW + j * 16 + l16) * 32 + quad * 8];
#pragma unroll
    for (int i = 0; i < MI; ++i)
#pragma unroll
      for (int j = 0; j < NI; ++j)
        acc[i][j] = __builtin_amdgcn_mfma_f32_16x16x32_bf16(af[i], bf[j], acc[i][j], 0, 0, 0);
  }
}

// ---------------- QKV GEMM: [4096,1024]x[1024,3072] + bias ----------------
// Q plane: [2][16][2048][64] pre-scaled by 0.125*log2(e) (softmax in exp2 domain)
// K plane: [2][16][2048][64]
// V plane: TRANSPOSED [2][16][64][2048]
__global__ __launch_bounds__(256) void qkv_gemm_kernel(
    const unsigned short* __restrict__ A,   // x bf16 [4096][1024]
    const unsigned short* __restrict__ WT,  // w_qkv^T bf16 [3072][1024]
    const float* __restrict__ bias,         // [3072]
    unsigned short* __restrict__ QKV)
{
  __shared__ unsigned short As[128 * 32];
  __shared__ unsigned short Bs[128 * 32];
  const int lane = threadIdx.x & 63;
  const int wave = threadIdx.x >> 6;
  const int l16 = lane & 15, quad = lane >> 4;

  f32x4 acc[4][4];
  const f32x4 z4 = {0.f, 0.f, 0.f, 0.f};
#pragma unroll
  for (int i = 0; i < 4; ++i)
#pragma unroll
    for (int j = 0; j < 4; ++j) acc[i][j] = z4;

  gemm_mainloop<4, 4>(A, WT, 1024, blockIdx.x * 128, blockIdx.y * 128,
                      As, Bs, acc, lane, wave);

  const int m0 = blockIdx.x * 128 + (wave >> 1) * 64;
  const int n0 = blockIdx.y * 128 + (wave & 1) * 64;
  const int whichW = n0 >> 10;          // uniform per wave (64 | 1024)
  const int bb = m0 >> 11;              // uniform per wave (64 | 2048)
  const int sBase = (m0 & 2047);
  const size_t planeE = (size_t)2 * 16 * 2048 * 64;

  if (whichW == 2) {                    // V -> transposed store
    unsigned short* Vb = QKV + 2 * planeE;
#pragma unroll
    for (int j = 0; j < 4; ++j) {
      const int rem = (n0 & 1023) + j * 16 + l16;
      const int hh = rem >> 6, hd = rem & 63;
      const float bv = bias[n0 + j * 16 + l16];
      unsigned short* col = Vb + (((size_t)bb * 16 + hh) * 64 + hd) * 2048;
#pragma unroll
      for (int i = 0; i < 4; ++i) {
        unsigned short pk[4];
#pragma unroll
        for (int r = 0; r < 4; ++r) pk[r] = f2bf(acc[i][j][r] + bv);
        *(ushort4*)&col[sBase + i * 16 + quad * 4] = *(ushort4*)pk;
      }
    }
  } else {
    // Q: fold 1/sqrt(Hd) AND log2(e) -> scores come out in log2 domain
    const float scale = (whichW == 0) ? 0.18033688011112042f : 1.0f;
#pragma unroll
    for (int j = 0; j < 4; ++j) {
      const int n = n0 + j * 16 + l16;
      const float bv = bias[n];
      const int rem = n & 1023;
      const int hh = rem >> 6, hd = rem & 63;
      unsigned short* pl = QKV + (size_t)whichW * planeE +
                           (((size_t)bb * 16 + hh) * 2048) * 64 + hd;
#pragma unroll
      for (int r = 0; r < 4; ++r) {
        const int s = sBase + (quad * 4 + r);
#pragma unroll
        for (int i = 0; i < 4; ++i)
          pl[(size_t)(s + i * 16) * 64] = f2bf((acc[i][j][r] + bv) * scale);
      }
    }
  }
}

// ---------------- flash attention (swapped 32x32, in-register P) ----------
// Block = (b, h, 128-query group), 4 waves x 32 queries. K/V 64-key tiles in
// 3 LDS buffers; stage(ti+2) issued each iter; barrier = s_waitcnt vmcnt(4)
// (leaves next tile's 4 DMAs in flight) + s_barrier. Only VMEM in the loop
// is the staging DMA, so the vmcnt ledger is exact; last iters re-stage a
// dummy tile to keep it so. Swizzle: 16B slot = row*8 + (c ^ (row&7)).
//
// S^T = mfma_32x32x16(K, Q): lane owns query lane&31; 16 scores/reg-file for
// keys (r&3)+8*(r>>2)+4*(lane>>5) (+kg*32). exp2 in f32, pack via
// v_cvt_pk_bf16_f32, redistribute lane<->lane+32 halves with
// v_permlane32_swap_b32 -> PV A-frags directly (no LDS). Row sums via an
// extra ones-column MFMA: Osum rows match O's query rows, so normalization
// needs no cross-lane traffic.
__global__ __launch_bounds__(256, 2) void attn_kernel(
    const unsigned short* __restrict__ QKV,
    unsigned short* __restrict__ AO)         // [2][2048][1024] bf16
{
  __shared__ __align__(16) unsigned short Ks[3 * 64 * 64];  // 24 KB
  __shared__ __align__(16) unsigned short Vs[3 * 64 * 64];  // 24 KB
  const int lane = threadIdx.x & 63;
  const int wave = threadIdx.x >> 6;
  const int l31 = lane & 31;
  const int hi  = lane >> 5;
  const int h = blockIdx.y, b = blockIdx.z;
  // complement pairing: co-resident z=0/z=1 blocks sum to uniform work
  const int qg = b ? blockIdx.x : (15 - blockIdx.x);
  const int qw = qg * 128 + wave * 32;       // this wave's first query

  const size_t planeE = (size_t)2 * 16 * 2048 * 64;
  const size_t bhS = ((size_t)b * 16 + h) * (size_t)(2048 * 64);
  const unsigned short* Q   = QKV + bhS;                 // [2048][64], pre-scaled
  const unsigned short* Kg  = QKV + planeE + bhS;        // [2048][64]
  const unsigned short* VTg = QKV + 2 * planeE + bhS;    // [64][2048]

  // Q B-frags: B[k=hd][n=query=l31]; frag t covers hd t*16 + hi*8 .. +7
  bf16x8 qf_[4];
#pragma unroll
  for (int t = 0; t < 4; ++t)
    qf_[t] = *(const bf16x8*)(Q + (size_t)(qw + l31) * 64 + t * 16 + hi * 8);

  bf16x8 onesf;                               // B-frag of bf16(1.0)
#pragma unroll
  for (int i = 0; i < 8; ++i) onesf[i] = (short)0x3F80;

  f32x16 O[2], Osum;
#pragma unroll
  for (int r = 0; r < 16; ++r) { O[0][r] = 0.f; O[1][r] = 0.f; Osum[r] = 0.f; }

  // DMA role: waves 0,1 stage K; waves 2,3 stage V. 4 instr/wave, 1KB each.
  const int tbase = (wave & 1) * 4;
  const bool doV = wave >= 2;

  auto stage = [&](int tileIdx, int bufIdx) {
    const int kt = tileIdx * 64;
    unsigned short* Kb = Ks + bufIdx * 4096;
    unsigned short* Vb = Vs + bufIdx * 4096;
#pragma unroll
    for (int i = 0; i < 4; ++i) {
      const int t = tbase + i;
      const int s = t * 64 + lane;           // 16B slot this lane fills
      const int row = s >> 3;
      const int c = (s & 7) ^ (row & 7);     // un-swizzle: which global 16B
      if (doV)
        async_load16(VTg + (size_t)row * 2048 + kt + c * 8, Vb + t * 512);
      else
        async_load16(Kg + (size_t)(kt + row) * 64 + c * 8, Kb + t * 512);
    }
  };

  const int nt = qg * 2 + 2;                 // staged tiles (covers wave 3)
  stage(0, 0);
  stage(1, 1);
  for (int ti = 0; ti < nt; ++ti) {
    // wait for stage(ti) (leaves the 4 newest = stage(ti+1) in flight),
    // then barrier. NO vmcnt(0) drain — the AITER-style pipeline.
    asm volatile("s_waitcnt vmcnt(4)\n\ts_barrier" ::: "memory");
    const int tn = (ti + 2 < nt) ? ti + 2 : nt - 1;  // dummy re-stage at the end
    stage(tn, (ti + 2) % 3);                 // keeps 4 in flight per wave, always
    const int kt = ti * 64;
    const unsigned short* Kb = Ks + (ti % 3) * 4096;
    const unsigned short* Vb = Vs + (ti % 3) * 4096;

    if (kt <= qw + 31) {
      const bool dmask = (kt + 63 > qw);
#pragma unroll
      for (int kg = 0; kg < 2; ++kg) {
        // K A-frags: A[m=key=l31(+kg*32)][k=hd chunk], swizzled LDS
        const int krow = kg * 32 + l31;
        const int ks7 = krow & 7;
        bf16x8 ka[4];
#pragma unroll
        for (int t = 0; t < 4; ++t)
          ka[t] = *(const bf16x8*)&Kb[(krow * 8 + ((t * 2 + hi) ^ ks7)) * 8];

        f32x16 sc;
#pragma unroll
        for (int r = 0; r < 16; ++r) sc[r] = 0.f;
        __builtin_amdgcn_s_setprio(1);
#pragma unroll
        for (int t = 0; t < 4; ++t)
          sc = __builtin_amdgcn_mfma_f32_32x32x16_bf16(ka[t], qf_[t], sc, 0, 0, 0);
        __builtin_amdgcn_s_setprio(0);

        // softmax term, fully in-register
        float p[16];
#pragma unroll
        for (int r = 0; r < 16; ++r) {
          float v = sc[r];
          if (dmask) {
            const int key = kt + kg * 32 + (r & 3) + 8 * (r >> 2) + 4 * hi;
            if (key > qw + l31) v = -INFINITY;
          }
          p[r] = EXP2(v);                    // native v_exp_f32
        }
        // pack pairs (keys ascend 2-at-a-time within each lane half)
        unsigned c8[8];
#pragma unroll
        for (int i = 0; i < 8; ++i)
          asm("v_cvt_pk_bf16_f32 %0, %1, %2"
              : "=v"(c8[i]) : "v"(p[2 * i]), "v"(p[2 * i + 1]));

#pragma unroll
        for (int half = 0; half < 2; ++half) {
          // assemble PV A-frag for 16-key chunk kc = kg*2+half:
          // lane half 0 needs keys kc*16+0..7, half 1 needs +8..15.
          unsigned a0 = c8[4 * half + 0], a1 = c8[4 * half + 1];
          unsigned a2 = c8[4 * half + 2], a3 = c8[4 * half + 3];
          asm("v_permlane32_swap_b32 %0, %1" : "+v"(a0), "+v"(a2));
          asm("v_permlane32_swap_b32 %0, %1" : "+v"(a1), "+v"(a3));
          union { unsigned u[4]; bf16x8 v; } pa;
          pa.u[0] = a0; pa.u[1] = a1; pa.u[2] = a2; pa.u[3] = a3;
          const int kc = kg * 2 + half;

          __builtin_amdgcn_s_setprio(1);
          // row-sum on the matrix pipe; lands in O's row layout
          Osum = __builtin_amdgcn_mfma_f32_32x32x16_bf16(pa.v, onesf, Osum, 0, 0, 0);
#pragma unroll
          for (int g = 0; g < 2; ++g) {
            const int vrow = g * 32 + l31;   // hd row of V^T
            bf16x8 vb = *(const bf16x8*)&Vb[(vrow * 8 + ((kc * 2 + hi) ^ (vrow & 7))) * 8];
            O[g] = __builtin_amdgcn_mfma_f32_32x32x16_bf16(pa.v, vb, O[g], 0, 0, 0);
          }
          __builtin_amdgcn_s_setprio(0);
        }
      }
    }
  }

  // epilogue: normalize by Osum (already per-row, replicated across lanes)
  unsigned short* base = AO + ((size_t)b * 2048 + qw) * 1024 + h * 64 + l31;
#pragma unroll
  for (int r = 0; r < 16; ++r) {
    const float inv = 1.0f / Osum[r];
    const int row = (r & 3) + 8 * (r >> 2) + 4 * hi;
#pragma unroll
    for (int g = 0; g < 2; ++g)
      base[(size_t)row * 1024 + g * 32] = f2bf(O[g][r] * inv);
  }
}

// ---------------- proj GEMM: [4096,1024]x[1024,1024] + bias -> fp32 out ----------------
// 64x128 block tile -> grid 64x8 = 512 blocks (2/CU)
__global__ __launch_bounds__(256) void proj_gemm_kernel(
    const unsigned short* __restrict__ A,   // AO bf16 [4096][1024]
    const unsigned short* __restrict__ WT,  // w_proj^T bf16 [1024][1024]
    const float* __restrict__ bias,         // [1024]
    float* __restrict__ out)                // [4096][1024] fp32
{
  __shared__ unsigned short As[64 * 32];
  __shared__ unsigned short Bs[128 * 32];
  const int lane = threadIdx.x & 63;
  const int wave = threadIdx.x >> 6;
  const int l16 = lane & 15, quad = lane >> 4;

  f32x4 acc[2][4];
  const f32x4 z4 = {0.f, 0.f, 0.f, 0.f};
#pragma unroll
  for (int i = 0; i < 2; ++i)
#pragma unroll
    for (int j = 0; j < 4; ++j) acc[i][j] = z4;

  gemm_mainloop<2, 4>(A, WT, 1024, blockIdx.x * 64, blockIdx.y * 128,
                      As, Bs, acc, lane, wave);

  const int m0 = blockIdx.x * 64 + (wave >> 1) * 32;
  const int n0 = blockIdx.y * 128 + (wave & 1) * 64;
#pragma unroll
  for (int i = 0; i < 2; ++i) {
#pragma unroll
    for (int j = 0; j < 4; ++j) {
      const int n = n0 + j * 16 + l16;
      const float bv = bias[n];
#pragma unroll
      for (int r = 0; r < 4; ++r) {
        const int m = m0 + i * 16 + quad * 4 + r;
        out[(size_t)m * 1024 + n] = acc[i][j][r] + bv;
      }
    }
  }
}

extern "C" void kernel_launch(void* const* d_in, const int* in_sizes, int n_in,
                              void* d_out, int out_size, void* d_ws, size_t ws_size,
                              hipStream_t stream) {
  const float* x      = (const float*)d_in[0];  // [2,2048,1024]
  const float* w_qkv  = (const float*)d_in[1];  // [1024,3072]
  const float* b_qkv  = (const float*)d_in[2];  // [3072]
  const float* w_proj = (const float*)d_in[3];  // [1024,1024]
  const float* b_proj = (const float*)d_in[4];  // [1024]
  float* out = (float*)d_out;                   // [2,2048,1024] fp32

  // workspace layout (ushort elems): Xb 4M | WTq 3M | WTp 1M | QKV 12M | AO 4M = 48 MiB
  unsigned short* Xb  = (unsigned short*)d_ws;
  unsigned short* WTq = Xb + (size_t)4096 * 1024;
  unsigned short* WTp = WTq + (size_t)3072 * 1024;
  unsigned short* QKV = WTp + (size_t)1024 * 1024;
  unsigned short* AO  = QKV + (size_t)3 * 4096 * 1024;

  f32_to_bf16_kernel<<<4096, 256, 0, stream>>>(x, Xb, 4096 * 1024);
  transpose_f32_bf16_kernel<<<dim3(96, 32), dim3(32, 8), 0, stream>>>(w_qkv, WTq, 1024, 3072);
  transpose_f32_bf16_kernel<<<dim3(32, 32), dim3(32, 8), 0, stream>>>(w_proj, WTp, 1024, 1024);
  qkv_gemm_kernel<<<dim3(32, 24), 256, 0, stream>>>(Xb, WTq, b_qkv, QKV);
  attn_kernel<<<dim3(16, 16, 2), 256, 0, stream>>>(QKV, AO);
  proj_gemm_kernel<<<dim3(64, 8), 256, 0, stream>>>(AO, WTp, b_proj, out);
}

// Round 3
// 201.510 us; speedup vs baseline: 1.0124x; 1.0012x over previous
//
#include <hip/hip_runtime.h>

// CausalSelfAttention: B=2, S=2048, D=1024, H=16, Hd=64
// qkv = x@w_qkv+b ; per-head causal softmax(QK^T/8)V ; out = ao@w_proj+b
//
// Fragment layouts (gfx950, HW-verified per guide):
//   16x16x32: A[m=lane&15][k=(lane>>4)*8+j]; B[k][n=lane&15]; C/D col=lane&15,
//             row=(lane>>4)*4+reg
//   32x32x16: A[m=lane&31][k=(lane>>5)*8+j]; B[k=(lane>>5)*8+j][n=lane&31];
//             C/D col=lane&31, row=(reg&3)+8*(reg>>2)+4*(lane>>5)  [m74/m101]
//
// Attention (R12 = R1-proven body + XCD remap ONLY; R2's pipeline restructure
// NaN'd and is reverted pending bisect): swapped 32x32 QK^T, P fully in
// registers (T12: cvt_pk + permlane32_swap), row-sums via ones-column MFMA.
// Triple-buffered K/V staging, prefetch distance 2, RAW barrier =
// s_waitcnt vmcnt(4); s_barrier (never vmcnt(0), AITER-style).
// XCD remap: lin&7 = XCD, 4 (b,h) columns pinned per XCD (K/V 2MB fits the
// 4MB per-XCD L2); CU c gets slots c and c+32 -> complement qg pair.
// p = exp2(score); log2e folded into Q pre-scale. setprio around MFMAs (T5).

typedef float f32x4 __attribute__((ext_vector_type(4)));
typedef float f32x16 __attribute__((ext_vector_type(16)));
typedef short bf16x8 __attribute__((ext_vector_type(8)));

#if __has_builtin(__builtin_amdgcn_exp2f)
#define EXP2(x) __builtin_amdgcn_exp2f(x)
#else
#define EXP2(x) exp2f(x)
#endif

__device__ __forceinline__ unsigned short f2bf(float f) {
  union { float f; unsigned u; } v; v.f = f;
  unsigned u = v.u + 0x7fffu + ((v.u >> 16) & 1u);   // RNE
  return (unsigned short)(u >> 16);
}

// async global->LDS, 16 bytes per lane; lds base must be wave-uniform,
// lane l's data lands at lds_base + l*16 bytes (m104/m108 semantics).
__device__ __forceinline__ void async_load16(const void* g, void* lds) {
  __builtin_amdgcn_global_load_lds(
      (const __attribute__((address_space(1))) void*)g,
      (__attribute__((address_space(3))) void*)lds, 16, 0, 0);
}

// ---------------- prep: fp32 -> bf16 elementwise ----------------
__global__ void f32_to_bf16_kernel(const float* __restrict__ in,
                                   unsigned short* __restrict__ out, int n) {
  int i = (blockIdx.x * 256 + threadIdx.x) * 4;
  if (i < n) {
    float4 f = *(const float4*)(in + i);
    ushort4 o;
    o.x = f2bf(f.x); o.y = f2bf(f.y); o.z = f2bf(f.z); o.w = f2bf(f.w);
    *(ushort4*)(out + i) = o;
  }
}

// ---------------- prep: fp32 [K][N] -> bf16 [N][K] ----------------
__global__ void transpose_f32_bf16_kernel(const float* __restrict__ in,
                                          unsigned short* __restrict__ out,
                                          int K, int N) {
  __shared__ float tile[32][33];
  int n0 = blockIdx.x * 32, k0 = blockIdx.y * 32;
  int tx = threadIdx.x, ty = threadIdx.y;  // block (32,8)
#pragma unroll
  for (int i = ty; i < 32; i += 8)
    tile[i][tx] = in[(size_t)(k0 + i) * N + (n0 + tx)];
  __syncthreads();
#pragma unroll
  for (int i = ty; i < 32; i += 8)
    out[(size_t)(n0 + i) * K + (k0 + tx)] = f2bf(tile[tx][i]);
}

// ---------------- shared GEMM mainloop (m97 structure) ----------------
template <int MI, int NI>
__device__ __forceinline__ void gemm_mainloop(
    const unsigned short* __restrict__ A,   // [M][K] row-major bf16
    const unsigned short* __restrict__ BT,  // [N][K] row-major bf16
    int K, int mBlk, int nBlk,
    unsigned short* As, unsigned short* Bs,
    f32x4 (&acc)[MI][NI], int lane, int wave)
{
  const int l16 = lane & 15, quad = lane >> 4;
  const int mW = (wave >> 1) * MI * 16;
  const int nW = (wave & 1) * NI * 16;
  constexpr int AROWS = 2 * MI * 16;
  constexpr int BROWS = 2 * NI * 16;
  constexpr int AINST = AROWS / 64;
  constexpr int BINST = BROWS / 64;
  const int rl = lane >> 2;           // 16 rows per instruction
  const int cl = (lane & 3) * 8;      // 4 lanes cover one 32-elem row

  for (int k0 = 0; k0 < K; k0 += 32) {
    __syncthreads();
#pragma unroll
    for (int t = 0; t < AINST; ++t) {
      const int rbase = wave * (AROWS / 4) + t * 16;
      async_load16(A + (size_t)(mBlk + rbase + rl) * K + k0 + cl, &As[rbase * 32]);
    }
#pragma unroll
    for (int t = 0; t < BINST; ++t) {
      const int rbase = wave * (BROWS / 4) + t * 16;
      async_load16(BT + (size_t)(nBlk + rbase + rl) * K + k0 + cl, &Bs[rbase * 32]);
    }
    __syncthreads();

    bf16x8 af[MI], bf[NI];
#pragma unroll
    for (int i = 0; i < MI; ++i)
      af[i] = *(const bf16x8*)&As[(mW + i * 16 + l16) * 32 + quad * 8];
#pragma unroll
    for (int j = 0; j < NI; ++j)
      bf[j] = *(const bf16x8*)&Bs[(nW + j * 16 + l16) * 32 + quad * 8];
#pragma unroll
    for (int i = 0; i < MI; ++i)
#pragma unroll
      for (int j = 0; j < NI; ++j)
        acc[i][j] = __builtin_amdgcn_mfma_f32_16x16x32_bf16(af[i], bf[j], acc[i][j], 0, 0, 0);
  }
}

// ---------------- QKV GEMM: [4096,1024]x[1024,3072] + bias ----------------
// Q plane: [2][16][2048][64] pre-scaled by 0.125*log2(e) (softmax in exp2 domain)
// K plane: [2][16][2048][64]
// V plane: TRANSPOSED [2][16][64][2048]
__global__ __launch_bounds__(256) void qkv_gemm_kernel(
    const unsigned short* __restrict__ A,   // x bf16 [4096][1024]
    const unsigned short* __restrict__ WT,  // w_qkv^T bf16 [3072][1024]
    const float* __restrict__ bias,         // [3072]
    unsigned short* __restrict__ QKV)
{
  __shared__ unsigned short As[128 * 32];
  __shared__ unsigned short Bs[128 * 32];
  const int lane = threadIdx.x & 63;
  const int wave = threadIdx.x >> 6;
  const int l16 = lane & 15, quad = lane >> 4;

  f32x4 acc[4][4];
  const f32x4 z4 = {0.f, 0.f, 0.f, 0.f};
#pragma unroll
  for (int i = 0; i < 4; ++i)
#pragma unroll
    for (int j = 0; j < 4; ++j) acc[i][j] = z4;

  gemm_mainloop<4, 4>(A, WT, 1024, blockIdx.x * 128, blockIdx.y * 128,
                      As, Bs, acc, lane, wave);

  const int m0 = blockIdx.x * 128 + (wave >> 1) * 64;
  const int n0 = blockIdx.y * 128 + (wave & 1) * 64;
  const int whichW = n0 >> 10;          // uniform per wave (64 | 1024)
  const int bb = m0 >> 11;              // uniform per wave (64 | 2048)
  const int sBase = (m0 & 2047);
  const size_t planeE = (size_t)2 * 16 * 2048 * 64;

  if (whichW == 2) {                    // V -> transposed store
    unsigned short* Vb = QKV + 2 * planeE;
#pragma unroll
    for (int j = 0; j < 4; ++j) {
      const int rem = (n0 & 1023) + j * 16 + l16;
      const int hh = rem >> 6, hd = rem & 63;
      const float bv = bias[n0 + j * 16 + l16];
      unsigned short* col = Vb + (((size_t)bb * 16 + hh) * 64 + hd) * 2048;
#pragma unroll
      for (int i = 0; i < 4; ++i) {
        unsigned short pk[4];
#pragma unroll
        for (int r = 0; r < 4; ++r) pk[r] = f2bf(acc[i][j][r] + bv);
        *(ushort4*)&col[sBase + i * 16 + quad * 4] = *(ushort4*)pk;
      }
    }
  } else {
    // Q: fold 1/sqrt(Hd) AND log2(e) -> scores come out in log2 domain
    const float scale = (whichW == 0) ? 0.18033688011112042f : 1.0f;
#pragma unroll
    for (int j = 0; j < 4; ++j) {
      const int n = n0 + j * 16 + l16;
      const float bv = bias[n];
      const int rem = n & 1023;
      const int hh = rem >> 6, hd = rem & 63;
      unsigned short* pl = QKV + (size_t)whichW * planeE +
                           (((size_t)bb * 16 + hh) * 2048) * 64 + hd;
#pragma unroll
      for (int r = 0; r < 4; ++r) {
        const int s = sBase + (quad * 4 + r);
#pragma unroll
        for (int i = 0; i < 4; ++i)
          pl[(size_t)(s + i * 16) * 64] = f2bf((acc[i][j][r] + bv) * scale);
      }
    }
  }
}

// ---------------- flash attention (swapped 32x32, in-register P) ----------
// Block = 4 waves x 32 queries = 128 queries of one (b,h). Linear grid 512:
//   xcd = lin&7, slot = lin>>3; col = xcd*4 + (slot>>4); b = col>>4, h = col&15
//   qg = slot<32 ? slot&15 : 15-(slot&15)
// -> each XCD sees only 4 (b,h) columns (2MB K/V, L2-resident); CU c within
// an XCD gets slots c and c+32 -> qg complement pair (balanced work).
// Body is the R1-proven schedule: per tile QK -> softmax -> PV, 3 buffers.
__global__ __launch_bounds__(256, 2) void attn_kernel(
    const unsigned short* __restrict__ QKV,
    unsigned short* __restrict__ AO)         // [2][2048][1024] bf16
{
  __shared__ __align__(16) unsigned short Ks[3 * 64 * 64];  // 24 KB
  __shared__ __align__(16) unsigned short Vs[3 * 64 * 64];  // 24 KB
  const int lane = threadIdx.x & 63;
  const int wave = threadIdx.x >> 6;
  const int l31 = lane & 31;
  const int hi  = lane >> 5;

  const int lin  = blockIdx.x;
  const int xcd  = lin & 7;
  const int slot = lin >> 3;                 // 0..63
  const int col  = xcd * 4 + (slot >> 4);    // 0..31
  const int b = col >> 4, h = col & 15;
  const int qg = (slot < 32) ? (slot & 15) : (15 - (slot & 15));
  const int qw = qg * 128 + wave * 32;       // this wave's first query

  const size_t planeE = (size_t)2 * 16 * 2048 * 64;
  const size_t bhS = ((size_t)b * 16 + h) * (size_t)(2048 * 64);
  const unsigned short* Q   = QKV + bhS;                 // [2048][64], pre-scaled
  const unsigned short* Kg  = QKV + planeE + bhS;        // [2048][64]
  const unsigned short* VTg = QKV + 2 * planeE + bhS;    // [64][2048]

  // Q B-frags: B[k=hd][n=query=l31]; frag t covers hd t*16 + hi*8 .. +7
  bf16x8 qf_[4];
#pragma unroll
  for (int t = 0; t < 4; ++t)
    qf_[t] = *(const bf16x8*)(Q + (size_t)(qw + l31) * 64 + t * 16 + hi * 8);

  bf16x8 onesf;                               // B-frag of bf16(1.0)
#pragma unroll
  for (int i = 0; i < 8; ++i) onesf[i] = (short)0x3F80;

  f32x16 O[2], Osum;
#pragma unroll
  for (int r = 0; r < 16; ++r) { O[0][r] = 0.f; O[1][r] = 0.f; Osum[r] = 0.f; }

  // DMA role: waves 0,1 stage K; waves 2,3 stage V. 4 instr/wave, 1KB each.
  const int tbase = (wave & 1) * 4;
  const bool doV = wave >= 2;

  auto stage = [&](int tileIdx, int bufIdx) {
    const int kt = tileIdx * 64;
    unsigned short* Kb = Ks + bufIdx * 4096;
    unsigned short* Vb = Vs + bufIdx * 4096;
#pragma unroll
    for (int i = 0; i < 4; ++i) {
      const int t = tbase + i;
      const int s = t * 64 + lane;           // 16B slot this lane fills
      const int row = s >> 3;
      const int c = (s & 7) ^ (row & 7);     // un-swizzle: which global 16B
      if (doV)
        async_load16(VTg + (size_t)row * 2048 + kt + c * 8, Vb + t * 512);
      else
        async_load16(Kg + (size_t)(kt + row) * 64 + c * 8, Kb + t * 512);
    }
  };

  const int nt = qg * 2 + 2;                 // staged tiles (covers wave 3)
  stage(0, 0);
  stage(1, 1);
  for (int ti = 0; ti < nt; ++ti) {
    // wait for stage(ti) (leaves the 4 newest = stage(ti+1) in flight),
    // then barrier. NO vmcnt(0) drain — the AITER-style pipeline.
    asm volatile("s_waitcnt vmcnt(4)\n\ts_barrier" ::: "memory");
    const int tn = (ti + 2 < nt) ? ti + 2 : nt - 1;  // dummy re-stage at the end
    stage(tn, (ti + 2) % 3);                 // keeps 4 in flight per wave, always
    const int kt = ti * 64;
    const unsigned short* Kb = Ks + (ti % 3) * 4096;
    const unsigned short* Vb = Vs + (ti % 3) * 4096;

    if (kt <= qw + 31) {
      const bool dmask = (kt + 63 > qw);
#pragma unroll
      for (int kg = 0; kg < 2; ++kg) {
        // K A-frags: A[m=key=l31(+kg*32)][k=hd chunk], swizzled LDS
        const int krow = kg * 32 + l31;
        const int ks7 = krow & 7;
        bf16x8 ka[4];
#pragma unroll
        for (int t = 0; t < 4; ++t)
          ka[t] = *(const bf16x8*)&Kb[(krow * 8 + ((t * 2 + hi) ^ ks7)) * 8];

        f32x16 sc;
#pragma unroll
        for (int r = 0; r < 16; ++r) sc[r] = 0.f;
        __builtin_amdgcn_s_setprio(1);
#pragma unroll
        for (int t = 0; t < 4; ++t)
          sc = __builtin_amdgcn_mfma_f32_32x32x16_bf16(ka[t], qf_[t], sc, 0, 0, 0);
        __builtin_amdgcn_s_setprio(0);

        // softmax term, fully in-register
        float p[16];
#pragma unroll
        for (int r = 0; r < 16; ++r) {
          float v = sc[r];
          if (dmask) {
            const int key = kt + kg * 32 + (r & 3) + 8 * (r >> 2) + 4 * hi;
            if (key > qw + l31) v = -INFINITY;
          }
          p[r] = EXP2(v);                    // native v_exp_f32
        }
        // pack pairs (keys ascend 2-at-a-time within each lane half)
        unsigned c8[8];
#pragma unroll
        for (int i = 0; i < 8; ++i)
          asm("v_cvt_pk_bf16_f32 %0, %1, %2"
              : "=v"(c8[i]) : "v"(p[2 * i]), "v"(p[2 * i + 1]));

#pragma unroll
        for (int half = 0; half < 2; ++half) {
          // assemble PV A-frag for 16-key chunk kc = kg*2+half:
          // lane half 0 needs keys kc*16+0..7, half 1 needs +8..15.
          unsigned a0 = c8[4 * half + 0], a1 = c8[4 * half + 1];
          unsigned a2 = c8[4 * half + 2], a3 = c8[4 * half + 3];
          asm("v_permlane32_swap_b32 %0, %1" : "+v"(a0), "+v"(a2));
          asm("v_permlane32_swap_b32 %0, %1" : "+v"(a1), "+v"(a3));
          union { unsigned u[4]; bf16x8 v; } pa;
          pa.u[0] = a0; pa.u[1] = a1; pa.u[2] = a2; pa.u[3] = a3;
          const int kc = kg * 2 + half;

          __builtin_amdgcn_s_setprio(1);
          // row-sum on the matrix pipe; lands in O's row layout
          Osum = __builtin_amdgcn_mfma_f32_32x32x16_bf16(pa.v, onesf, Osum, 0, 0, 0);
#pragma unroll
          for (int g = 0; g < 2; ++g) {
            const int vrow = g * 32 + l31;   // hd row of V^T
            bf16x8 vb = *(const bf16x8*)&Vb[(vrow * 8 + ((kc * 2 + hi) ^ (vrow & 7))) * 8];
            O[g] = __builtin_amdgcn_mfma_f32_32x32x16_bf16(pa.v, vb, O[g], 0, 0, 0);
          }
          __builtin_amdgcn_s_setprio(0);
        }
      }
    }
  }

  // epilogue: normalize by Osum (already per-row, replicated across lanes)
  unsigned short* base = AO + ((size_t)b * 2048 + qw) * 1024 + h * 64 + l31;
#pragma unroll
  for (int r = 0; r < 16; ++r) {
    const float inv = 1.0f / Osum[r];
    const int row = (r & 3) + 8 * (r >> 2) + 4 * hi;
#pragma unroll
    for (int g = 0; g < 2; ++g)
      base[(size_t)row * 1024 + g * 32] = f2bf(O[g][r] * inv);
  }
}

// ---------------- proj GEMM: [4096,1024]x[1024,1024] + bias -> fp32 out ----------------
// 64x128 block tile -> grid 64x8 = 512 blocks (2/CU)
__global__ __launch_bounds__(256) void proj_gemm_kernel(
    const unsigned short* __restrict__ A,   // AO bf16 [4096][1024]
    const unsigned short* __restrict__ WT,  // w_proj^T bf16 [1024][1024]
    const float* __restrict__ bias,         // [1024]
    float* __restrict__ out)                // [4096][1024] fp32
{
  __shared__ unsigned short As[64 * 32];
  __shared__ unsigned short Bs[128 * 32];
  const int lane = threadIdx.x & 63;
  const int wave = threadIdx.x >> 6;
  const int l16 = lane & 15, quad = lane >> 4;

  f32x4 acc[2][4];
  const f32x4 z4 = {0.f, 0.f, 0.f, 0.f};
#pragma unroll
  for (int i = 0; i < 2; ++i)
#pragma unroll
    for (int j = 0; j < 4; ++j) acc[i][j] = z4;

  gemm_mainloop<2, 4>(A, WT, 1024, blockIdx.x * 64, blockIdx.y * 128,
                      As, Bs, acc, lane, wave);

  const int m0 = blockIdx.x * 64 + (wave >> 1) * 32;
  const int n0 = blockIdx.y * 128 + (wave & 1) * 64;
#pragma unroll
  for (int i = 0; i < 2; ++i) {
#pragma unroll
    for (int j = 0; j < 4; ++j) {
      const int n = n0 + j * 16 + l16;
      const float bv = bias[n];
#pragma unroll
      for (int r = 0; r < 4; ++r) {
        const int m = m0 + i * 16 + quad * 4 + r;
        out[(size_t)m * 1024 + n] = acc[i][j][r] + bv;
      }
    }
  }
}

extern "C" void kernel_launch(void* const* d_in, const int* in_sizes, int n_in,
                              void* d_out, int out_size, void* d_ws, size_t ws_size,
                              hipStream_t stream) {
  const float* x      = (const float*)d_in[0];  // [2,2048,1024]
  const float* w_qkv  = (const float*)d_in[1];  // [1024,3072]
  const float* b_qkv  = (const float*)d_in[2];  // [3072]
  const float* w_proj = (const float*)d_in[3];  // [1024,1024]
  const float* b_proj = (const float*)d_in[4];  // [1024]
  float* out = (float*)d_out;                   // [2,2048,1024] fp32

  // workspace layout (ushort elems): Xb 4M | WTq 3M | WTp 1M | QKV 12M | AO 4M = 48 MiB
  unsigned short* Xb  = (unsigned short*)d_ws;
  unsigned short* WTq = Xb + (size_t)4096 * 1024;
  unsigned short* WTp = WTq + (size_t)3072 * 1024;
  unsigned short* QKV = WTp + (size_t)1024 * 1024;
  unsigned short* AO  = QKV + (size_t)3 * 4096 * 1024;

  f32_to_bf16_kernel<<<4096, 256, 0, stream>>>(x, Xb, 4096 * 1024);
  transpose_f32_bf16_kernel<<<dim3(96, 32), dim3(32, 8), 0, stream>>>(w_qkv, WTq, 1024, 3072);
  transpose_f32_bf16_kernel<<<dim3(32, 32), dim3(32, 8), 0, stream>>>(w_proj, WTp, 1024, 1024);
  qkv_gemm_kernel<<<dim3(32, 24), 256, 0, stream>>>(Xb, WTq, b_qkv, QKV);
  attn_kernel<<<512, 256, 0, stream>>>(QKV, AO);
  proj_gemm_kernel<<<dim3(64, 8), 256, 0, stream>>>(AO, WTp, b_proj, out);
}